// Round 15
// baseline (4319.707 us; speedup 1.0000x reference)
//
#include <hip/hip_runtime.h>

#define HW_ (512 * 512)
#define B_ 8
#define H_ 512
#define W_ 512
#define K_ 32
#define CH_ 16
#define CHPIX_ (HW_ / CH_)  // 16384 pixels per chunk

typedef float float2v __attribute__((ext_vector_type(2)));

// ---------------- compact phase A: per-chunk valid count ----------------
__global__ void k_count(const float* __restrict__ seg, int* __restrict__ chunkCnt) {
  const int blk = blockIdx.x;  // b*CH_ + c
  const int t = threadIdx.x;
  const float4* __restrict__ s4 = (const float4*)(seg + (size_t)blk * CHPIX_) + (size_t)t * 16;
  int cnt = 0;
#pragma unroll
  for (int j = 0; j < 16; ++j) {
    float4 v = s4[j];
    cnt += (v.x >= 0.9f) + (v.y >= 0.9f) + (v.z >= 0.9f) + (v.w >= 0.9f);
  }
  __shared__ int red[256];
  red[t] = cnt;
  __syncthreads();
  for (int off = 128; off > 0; off >>= 1) {
    if (t < off) red[t] += red[t + off];
    __syncthreads();
  }
  if (t == 0) chunkCnt[blk] = red[0];
}

// ---------------- compact phase B: per-batch chunk base offsets ----------------
__global__ void k_scan(const int* __restrict__ chunkCnt, int* __restrict__ chunkBase,
                       int* __restrict__ nvalid, int cap) {
  const int t = threadIdx.x;  // b*CH_ + c
  if (t < B_ * CH_) {
    const int b = t / CH_, c = t % CH_;
    int base = 0;
    for (int q = 0; q < c; ++q) base += chunkCnt[b * CH_ + q];
    chunkBase[t] = base;
    if (c == CH_ - 1) nvalid[b] = min(base + chunkCnt[t], cap);
  }
}

// ---------------- compact phase C: compaction + DUPLICATED gather + lanes memset ----------------
// embC layout: per valid pixel 16 floats: (e0,e0,e1,e1,...,e7,e7) so that a
// ds_read_b128 later yields natural (e_d,e_d) float2v splats for pk math.
__global__ void k_fill(const float* __restrict__ seg, const float* __restrict__ emb,
                       const int* __restrict__ chunkBase, unsigned char* __restrict__ lanes,
                       int* __restrict__ idxC, float* __restrict__ embC, int cap) {
  const int blk = blockIdx.x;  // b*CH_ + c
  const int b = blk / CH_;
  const int t = threadIdx.x;
  const size_t pixbase = (size_t)blk * CHPIX_ + (size_t)t * 64;
  const float4* __restrict__ s4 = (const float4*)(seg + pixbase);

  int cnt = 0;
#pragma unroll
  for (int j = 0; j < 16; ++j) {
    float4 v = s4[j];
    cnt += (v.x >= 0.9f) + (v.y >= 0.9f) + (v.z >= 0.9f) + (v.w >= 0.9f);
  }
  __shared__ int pre[256];
  pre[t] = cnt;
  __syncthreads();
  for (int off = 1; off < 256; off <<= 1) {
    int mine = pre[t];
    int add = (t >= off) ? pre[t - off] : 0;
    __syncthreads();
    pre[t] = mine + add;
    __syncthreads();
  }
  int w = chunkBase[blk] + pre[t] - cnt;

  uint4 z = {0u, 0u, 0u, 0u};
  uint4* lz = (uint4*)(lanes + pixbase);
  lz[0] = z; lz[1] = z; lz[2] = z; lz[3] = z;

  const float* __restrict__ eb = emb + (size_t)b * 8 * HW_;
  const int pixInB = (int)(pixbase - (size_t)b * HW_);
  for (int j = 0; j < 16; ++j) {
    float4 v = s4[j];
    float sv[4] = {v.x, v.y, v.z, v.w};
#pragma unroll
    for (int q = 0; q < 4; ++q) {
      if (sv[q] >= 0.9f && w < cap) {
        const int p = pixInB + j * 4 + q;
        idxC[(size_t)b * cap + w] = p;
        float* dst = embC + ((size_t)b * cap + w) * 16;
#pragma unroll
        for (int dd = 0; dd < 8; ++dd) {
          float vv = eb[(size_t)dd * HW_ + p];
          dst[2 * dd] = vv;
          dst[2 * dd + 1] = vv;
        }
        ++w;
      }
    }
  }
}

// ---------------- sequential clustering: 4 batches/wave, 2 centers/lane ----------------
// 2 blocks x 1 wave. Group g = lanes [16g,16g+16) owns batch 4*blk+g.
// Lane (q = lane&15) holds centers q (lo half) and q+16 (hi half) of its batch
// in packed float2v registers (dim-major: C_d = (C_q[d], C_{q+16}[d])).
// e arrives duplicated from LDS (ds_read_b128 at group-uniform addr -> natural
// (e_d,e_d) splats; 4 groups at bank-offsets 8 apart = conflict-free broadcast).
// Min-reduce: per-lane min of 2 keys, then 4-level DPP butterfly over 16 lanes
// = ALL-reduce (every lane gets the group min) -> w is pure VALU, no readlane
// on the chain. Decision algebra (key = (dsq_bits&~31)|id, empty->inf, join
// dsq<9) bit-identical to validated R6-R13.

#define TILE_ 32

__device__ __forceinline__ void stage16(const float* g, float* l) {
  __builtin_amdgcn_global_load_lds(
      (const __attribute__((address_space(1))) void*)g,
      (__attribute__((address_space(3))) void*)l, 16, 0, 0);
}

#define PKF(A, B, C) __builtin_elementwise_fma((A), (B), (C))

// load slot LS with pixel P of this tile (group-uniform broadcast reads)
#define LOADSLOT(LS, EB, P)                                    \
  s##LS##a = *(const float4*)((EB) + (P) * 64);                \
  s##LS##b = *(const float4*)((EB) + (P) * 64 + 16);           \
  s##LS##c = *(const float4*)((EB) + (P) * 64 + 32);           \
  s##LS##d = *(const float4*)((EB) + (P) * 64 + 48);

// J: step 0..31 (pixel J of tile for ALL 4 batches). US = J%3, LS = (J+2)%3.
#define STEPQ(J, US, LS)                                                             \
  do {                                                                               \
    float2v e0 = {s##US##a.x, s##US##a.y}, e1 = {s##US##a.z, s##US##a.w};            \
    float2v e2 = {s##US##b.x, s##US##b.y}, e3 = {s##US##b.z, s##US##b.w};            \
    float2v e4 = {s##US##c.x, s##US##c.y}, e5 = {s##US##c.z, s##US##c.w};            \
    float2v e6 = {s##US##d.x, s##US##d.y}, e7 = {s##US##d.z, s##US##d.w};            \
    float2v t0 = C0 - e0, t1 = C1 - e1, t2 = C2 - e2, t3 = C3 - e3;                  \
    float2v t4 = C4 - e4, t5 = C5 - e5, t6 = C6 - e6, t7 = C7 - e7;                  \
    float2v pa = t0 * t0; pa = PKF(t1, t1, pa);                                      \
    float2v pb = t2 * t2; pb = PKF(t3, t3, pb);                                      \
    float2v pc = t4 * t4; pc = PKF(t5, t5, pc);                                      \
    float2v pd = t6 * t6; pd = PKF(t7, t7, pd);                                      \
    pa = pa + pb;                                                                    \
    pc = pc + pd;                                                                    \
    pa = pa + pc; /* pa = (dsqL, dsqH) */                                            \
    unsigned dL = __float_as_uint(pa.x);                                             \
    unsigned dH = __float_as_uint(pa.y);                                             \
    dL = dL > emL ? dL : emL; /* empty center -> inf bits */                         \
    dH = dH > emH ? dH : emH;                                                        \
    unsigned kL = (dL & 0xFFFFFFE0u) | idL;                                          \
    unsigned kH = (dH & 0xFFFFFFE0u) | idH;                                          \
    unsigned mn = kL < kH ? kL : kH;                                                 \
    unsigned mr;                                                                     \
    mr = (unsigned)__builtin_amdgcn_update_dpp(0, (int)mn, 0xB1, 0xF, 0xF, true);    \
    mn = mn < mr ? mn : mr;                                                          \
    mr = (unsigned)__builtin_amdgcn_update_dpp(0, (int)mn, 0x4E, 0xF, 0xF, true);    \
    mn = mn < mr ? mn : mr;                                                          \
    mr = (unsigned)__builtin_amdgcn_update_dpp(0, (int)mn, 0x141, 0xF, 0xF, true);   \
    mn = mn < mr ? mn : mr;                                                          \
    mr = (unsigned)__builtin_amdgcn_update_dpp(0, (int)mn, 0x140, 0xF, 0xF, true);   \
    mn = mn < mr ? mn : mr; /* butterfly: ALL 16 lanes hold group min */             \
    bool join = mn < 0x41100000u; /* dsq < 9.0 <=> sqrt(dsq) < 3, exact */           \
    unsigned nactc = nactv < 31u ? nactv : 31u;                                      \
    float wLj = (kL == mn) ? inv2.x : 0.0f;                                          \
    float wHj = (kH == mn) ? inv2.y : 0.0f;                                          \
    float wLn = (idL == nactc) ? 1.0f : 0.0f;                                        \
    float wHn = (idH == nactc) ? 1.0f : 0.0f;                                        \
    float wL = join ? wLj : wLn;                                                     \
    float wH = join ? wHj : wHn;                                                     \
    float2v w2 = {wL, wH};                                                           \
    C0 = PKF(t0, -w2, C0); /* C -= w*t */                                            \
    C1 = PKF(t1, -w2, C1);                                                           \
    C2 = PKF(t2, -w2, C2);                                                           \
    C3 = PKF(t3, -w2, C3);                                                           \
    C4 = PKF(t4, -w2, C4);                                                           \
    C5 = PKF(t5, -w2, C5);                                                           \
    C6 = PKF(t6, -w2, C6);                                                           \
    C7 = PKF(t7, -w2, C7);                                                           \
    float2v ownf = {(wL > 0.0f) ? 1.0f : 0.0f, (wH > 0.0f) ? 1.0f : 0.0f};           \
    cnt2 = cnt2 + ownf;                                                              \
    float2v cp1 = cnt2 + one2;                                                       \
    inv2.x = __builtin_amdgcn_rcpf(cp1.x); /* off-chain: used next step */           \
    inv2.y = __builtin_amdgcn_rcpf(cp1.y);                                           \
    emL = (wL > 0.0f) ? 0u : emL;                                                    \
    emH = (wH > 0.0f) ? 0u : emH;                                                    \
    nactv += join ? 0u : 1u;                                                         \
    unsigned cid = join ? (mn & 31u) : nactc;                                        \
    pk |= (unsigned long long)(cid + 1u) << (((J) & 7) * 8);                         \
    if (((J) & 7) == 7) {                                                            \
      if (q16 == 0) *(unsigned long long*)(cpG + ((J) & ~7)) = pk;                   \
      pk = 0ULL;                                                                     \
    }                                                                                \
    if ((J) < TILE_ - 2) { LOADSLOT(LS, ebase, (J) + 2) }                            \
  } while (0)

__global__ __launch_bounds__(64, 1) void k_cluster(const float* __restrict__ embC,
                                                   const int* __restrict__ nvalid,
                                                   unsigned char* __restrict__ cidArr,
                                                   int cap) {
  // 2 phases x 4 regions x 2080 B (region stride 2080 = 2048 data + 32 pad so
  // group bases land 8 banks apart -> conflict-free 4-address broadcast reads)
  __shared__ float lds[4160];
  const int blk = blockIdx.x;  // 0..1
  const int lane = threadIdx.x;
  const int q16 = lane & 15;
  const int g = lane >> 4;
  const int bBase = blk * 4;
  const int n0 = nvalid[bBase], n1 = nvalid[bBase + 1];
  const int n2 = nvalid[bBase + 2], n3 = nvalid[bBase + 3];
  int nMax = n0 > n1 ? n0 : n1;
  nMax = nMax > n2 ? nMax : n2;
  nMax = nMax > n3 ? nMax : n3;
  if (nMax <= 0) return;
  const int nTiles = (nMax + TILE_ - 1) / TILE_;

  unsigned char* cpBase = cidArr + (size_t)(bBase + g) * HW_;

  float2v C0 = {0.f, 0.f}, C1 = C0, C2 = C0, C3 = C0, C4 = C0, C5 = C0, C6 = C0, C7 = C0;
  float2v cnt2 = {0.f, 0.f}, inv2 = {1.f, 1.f};
  const float2v one2 = {1.f, 1.f};
  unsigned emL = 0x7F800000u, emH = 0x7F800000u;
  const unsigned idL = (unsigned)q16, idH = (unsigned)q16 + 16u;
  unsigned nactv = 0u;
  unsigned long long pk = 0ULL;
  float4 s0a, s0b, s0c, s0d, s1a, s1b, s1c, s1d, s2a, s2b, s2c, s2d;

  // prologue: stage tile 0 (4 batches x 2KB), wait
  for (int bb = 0; bb < 4; ++bb) {
    const float* s = embC + (size_t)(bBase + bb) * cap * 16 + (size_t)lane * 4;
    stage16(s, lds + bb * 520);
    stage16(s + 256, lds + bb * 520 + 256);
  }
  asm volatile("s_waitcnt vmcnt(0)" ::: "memory");
  __builtin_amdgcn_sched_barrier(0);

  for (int ti = 0; ti < nTiles; ++ti) {
    const bool more = (ti + 1 < nTiles);
    const char* ebase = (const char*)lds + (ti & 1) * 8320 + g * 2080;
    unsigned char* cpG = cpBase + ti * TILE_;

    // slot prologue: pixels 0,1 of this tile (group-uniform broadcast reads)
    LOADSLOT(0, ebase, 0)
    LOADSLOT(1, ebase, 1)

    if (more) {  // stage next tile (4 batches) into the other phase
      const int ph = ((ti + 1) & 1) * 2080;
      for (int bb = 0; bb < 4; ++bb) {
        const float* s = embC + (size_t)(bBase + bb) * cap * 16 +
                         (size_t)(ti + 1) * 512 + (size_t)lane * 4;
        stage16(s, lds + ph + bb * 520);
        stage16(s + 256, lds + ph + bb * 520 + 256);
      }
    }

    STEPQ(0, 0, 2);  STEPQ(1, 1, 0);  STEPQ(2, 2, 1);  STEPQ(3, 0, 2);
    STEPQ(4, 1, 0);  STEPQ(5, 2, 1);  STEPQ(6, 0, 2);  STEPQ(7, 1, 0);
    STEPQ(8, 2, 1);  STEPQ(9, 0, 2);  STEPQ(10, 1, 0); STEPQ(11, 2, 1);
    STEPQ(12, 0, 2); STEPQ(13, 1, 0); STEPQ(14, 2, 1); STEPQ(15, 0, 2);
    STEPQ(16, 1, 0); STEPQ(17, 2, 1); STEPQ(18, 0, 2); STEPQ(19, 1, 0);
    STEPQ(20, 2, 1); STEPQ(21, 0, 2); STEPQ(22, 1, 0); STEPQ(23, 2, 1);
    STEPQ(24, 0, 2); STEPQ(25, 1, 0); STEPQ(26, 2, 1); STEPQ(27, 0, 2);
    STEPQ(28, 1, 0); STEPQ(29, 2, 1); STEPQ(30, 0, 2); STEPQ(31, 1, 0);

    if (more) {
      // outstanding VMEM (oldest->newest): <=4 prev-tile stores, 8 stages,
      // 4 this-tile stores. In-order retirement => vmcnt(4) <=> stages done.
      asm volatile("s_waitcnt vmcnt(4)" ::: "memory");
      __builtin_amdgcn_sched_barrier(0);
    }
  }
}

// ---------------- scatter cid bytes to the per-pixel lane map ----------------
__global__ void k_scatter(const unsigned char* __restrict__ cidArr,
                          const int* __restrict__ idxC, const int* __restrict__ nvalid,
                          unsigned char* __restrict__ lanes, int cap) {
  const int b = blockIdx.y;
  const int n = nvalid[b];
  for (int j = blockIdx.x * blockDim.x + threadIdx.x; j < n; j += gridDim.x * blockDim.x) {
    lanes[(size_t)b * HW_ + idxC[(size_t)b * cap + j]] = cidArr[(size_t)b * HW_ + j];
  }
}

// ---------------- per-(b,h) segment sums over 33 lane bins ----------------
__global__ void k_rowsum(const unsigned char* __restrict__ lanes,
                         const float* __restrict__ offp, const float* __restrict__ zp,
                         float* __restrict__ cnt, float* __restrict__ sx,
                         float* __restrict__ sz) {
  const int bh = blockIdx.x;
  const int b = bh >> 9, h = bh & 511;
  __shared__ float sc[33], sxx[33], szz[33];
  const int t = threadIdx.x;
  if (t < 33) { sc[t] = 0.f; sxx[t] = 0.f; szz[t] = 0.f; }
  __syncthreads();
  const size_t base = (size_t)bh * W_;
  for (int x = t; x < W_; x += 256) {
    int ln = lanes[base + x];
    float o = offp[base + x];
    float sig = 1.0f / (1.0f + expf(-o));
    float xa = (float)x + sig;
    float zv = zp[base + x];
    atomicAdd(&sc[ln], 1.0f);
    atomicAdd(&sxx[ln], xa);
    atomicAdd(&szz[ln], zv);
  }
  __syncthreads();
  if (t >= 1 && t < 33) {
    size_t o = ((size_t)b * K_ + (t - 1)) * H_ + h;
    cnt[o] = sc[t]; sx[o] = sxx[t]; sz[o] = szz[t];
  }
}

// ---------------- validity + point assembly ----------------
__global__ void k_final(const float* __restrict__ cnt, const float* __restrict__ sx,
                        const float* __restrict__ sz, float* __restrict__ out) {
  const int bk = blockIdx.x;
  const int b = bk >> 5, k = bk & 31;
  const int h = threadIdx.x;
  const size_t o = (size_t)bk * H_ + h;
  float c = cnt[o];
  float sc_ = c, sn = (c > 0.f) ? 1.f : 0.f;
#pragma unroll
  for (int off = 32; off >= 1; off >>= 1) {
    sc_ += __shfl_down(sc_, off);
    sn += __shfl_down(sn, off);
  }
  __shared__ float rs[8], rn[8], tot[2];
  const int wid = h >> 6, lid = h & 63;
  if (lid == 0) { rs[wid] = sc_; rn[wid] = sn; }
  __syncthreads();
  if (h == 0) {
    float a = 0, bb = 0;
#pragma unroll
    for (int q = 0; q < 8; ++q) { a += rs[q]; bb += rn[q]; }
    tot[0] = a; tot[1] = bb;
  }
  __syncthreads();
  float size = tot[0], nrows = tot[1];
  bool valid = (c > 0.f) && (size >= 50.f) && (nrows >= 2.f);
  float mx = sx[o] / fmaxf(c, 1.f);
  float mz = sz[o] / fmaxf(c, 1.f);
  float xw = (512.0f - ((float)h + 0.5f)) * 0.2f;
  float yw = -(mx - 256.0f) * 0.2f;
  out[((size_t)(b * 3 + 0) * K_ + k) * H_ + h] = valid ? xw : 0.f;
  out[((size_t)(b * 3 + 1) * K_ + k) * H_ + h] = valid ? yw : 0.f;
  out[((size_t)(b * 3 + 2) * K_ + k) * H_ + h] = valid ? mz : 0.f;
  out[(size_t)B_ * 3 * K_ * H_ + (size_t)bk * H_ + h] = valid ? 1.f : 0.f;
}

extern "C" void kernel_launch(void* const* d_in, const int* in_sizes, int n_in,
                              void* d_out, int out_size, void* d_ws, size_t ws_size,
                              hipStream_t stream) {
  const float* seg  = (const float*)d_in[0];
  const float* emb  = (const float*)d_in[1];
  const float* offp = (const float*)d_in[2];
  const float* zp   = (const float*)d_in[3];
  float* out = (float*)d_out;
  char* ws = (char*)d_ws;

  const size_t lanesOff = 0;
  const size_t cntOff   = (size_t)B_ * HW_;
  const size_t sxOff    = cntOff + (size_t)B_ * K_ * H_ * 4;
  const size_t szOff    = sxOff  + (size_t)B_ * K_ * H_ * 4;
  const size_t nvOff    = szOff  + (size_t)B_ * K_ * H_ * 4;
  const size_t ccOff    = nvOff + 256;
  const size_t cbOff    = ccOff + 1024;
  const size_t cidOff   = cbOff + 1024;                      // u8 [B][HW_] = 2 MiB
  const size_t idxOff   = cidOff + (size_t)B_ * HW_;
  size_t avail = (ws_size > idxOff + 16384) ? (ws_size - idxOff - 16384) : 0;  // staging slack
  long long capLL = (long long)(avail / ((size_t)B_ * 68));  // 4B idx + 64B dup-emb per entry
  if (capLL > (long long)HW_) capLL = HW_;
  if (capLL < 2) capLL = 2;
  capLL &= ~1LL;  // keep per-batch embC base 128B-aligned
  const int cap = (int)capLL;
  const size_t embOff = idxOff + (size_t)B_ * cap * 4;

  unsigned char* lanes = (unsigned char*)(ws + lanesOff);
  float* cnt = (float*)(ws + cntOff);
  float* sx  = (float*)(ws + sxOff);
  float* sz  = (float*)(ws + szOff);
  int* nvalid = (int*)(ws + nvOff);
  int* chunkCnt  = (int*)(ws + ccOff);
  int* chunkBase = (int*)(ws + cbOff);
  unsigned char* cidArr = (unsigned char*)(ws + cidOff);
  int* idxC   = (int*)(ws + idxOff);
  float* embC = (float*)(ws + embOff);

  k_count<<<B_ * CH_, 256, 0, stream>>>(seg, chunkCnt);
  k_scan<<<1, 128, 0, stream>>>(chunkCnt, chunkBase, nvalid, cap);
  k_fill<<<B_ * CH_, 256, 0, stream>>>(seg, emb, chunkBase, lanes, idxC, embC, cap);
  k_cluster<<<B_ / 4, 64, 0, stream>>>(embC, nvalid, cidArr, cap);
  k_scatter<<<dim3(64, B_), 256, 0, stream>>>(cidArr, idxC, nvalid, lanes, cap);
  k_rowsum<<<B_ * H_, 256, 0, stream>>>(lanes, offp, zp, cnt, sx, sz);
  k_final<<<B_ * K_, H_, 0, stream>>>(cnt, sx, sz, out);
}